// Round 14
// baseline (465.164 us; speedup 1.0000x reference)
//
#include <hip/hip_runtime.h>

#define N_NODES 500000
#define N_EDGES 8000000
#define N_GRAPHS 4096
#define IN_DIM 9
#define HID 64
#define TILE 128             // nodes per wave-private bucket (was 256)
#define TSR 12               // LDS tile row stride -> 48 B (f4,f4,scalar)
#define NKEYS 4096           // padded key space (used: 3907)
#define NKEYS_USED ((N_NODES + TILE - 1) / TILE)   // 3907
#define NSCAT 256            // hist/scatter chunks
#define CHUNK (N_EDGES / NSCAT)                    // 31250
#define HSB 1024             // hist/scatter block threads
#define RB 256               // reduce block threads (4 waves)
#define WPB 4
#define RGRID ((NKEYS_USED + WPB - 1) / WPB)       // 977
#define SCAN_N (NKEYS * NSCAT)                     // 1048576
#define SCAN_BLOCKS (SCAN_N / 1024)                // 1024
#define NW 8                 // src windows: src>>16
#define CAP 2560             // winsort LDS capacity (mean 2048, sd ~45)

// ---------------- xpad: x[N][9] -> xa[N][8] (32B rows) + xb[N] --------------
__global__ void gin_xpad(const float* __restrict__ x,
                         float* __restrict__ xa, float* __restrict__ xb) {
    int i = blockIdx.x * blockDim.x + threadIdx.x;
    const int TOT = N_NODES * IN_DIM;
    if (i < TOT) {
        int n = i / IN_DIM, k = i - n * IN_DIM;
        float val = x[i];
        if (k < 8) xa[n * 8 + k] = val;
        else       xb[n] = val;
    }
}

// ---------------- precompute: v = w2@w3, c = b2.w3, out[g] = b3 -------------
__global__ void gin_precompute(const float* __restrict__ w2,
                               const float* __restrict__ b2,
                               const float* __restrict__ w3,
                               const float* __restrict__ b3,
                               float* __restrict__ out,
                               float* __restrict__ v,
                               float* __restrict__ c) {
    int g = blockIdx.x * blockDim.x + threadIdx.x;
    if (g < N_GRAPHS) out[g] = b3[0];
    if (blockIdx.x == 0) {
        int k = threadIdx.x;
        if (k < HID) {
            float acc = 0.f;
            #pragma unroll
            for (int j = 0; j < HID; ++j) acc += w2[k * HID + j] * w3[j];
            v[k] = acc;
        } else if (k == HID) {
            float acc = 0.f;
            #pragma unroll
            for (int j = 0; j < HID; ++j) acc += b2[j] * w3[j];
            *c = acc;
        }
    }
}

// ---------------- hist: cnt[key*NSCAT + s], key = dst>>7 --------------------
__global__ __launch_bounds__(HSB) void gin_hist(const int* __restrict__ ei,
                                                int* __restrict__ cnt) {
    __shared__ int h[NKEYS];   // 16 KB
    const int t = threadIdx.x, s = blockIdx.x;
    for (int b = t; b < NKEYS; b += HSB) h[b] = 0;
    __syncthreads();
    const int* dst = ei + N_EDGES;
    const int e0 = s * CHUNK, e1 = e0 + CHUNK;
    for (int e = e0 + t; e < e1; e += HSB)
        atomicAdd(&h[dst[e] >> 7], 1);
    __syncthreads();
    for (int b = t; b < NKEYS; b += HSB)
        cnt[b * NSCAT + s] = h[b];
}

// ---------------- parallel exclusive scan of cnt[SCAN_N] --------------------
__global__ __launch_bounds__(256) void gin_scan_a(int* __restrict__ cnt,
                                                  int* __restrict__ aux) {
    __shared__ int wtot[4];
    const int t = threadIdx.x, blk = blockIdx.x;
    int4* p = (int4*)(cnt + blk * 1024);
    int4 vv = p[t];
    int s0 = vv.x, s1 = s0 + vv.y, s2 = s1 + vv.z, s3 = s2 + vv.w;
    int lane = t & 63, w = t >> 6;
    int ws = s3;
    #pragma unroll
    for (int off = 1; off < 64; off <<= 1) {
        int o = __shfl_up(ws, off);
        if (lane >= off) ws += o;
    }
    if (lane == 63) wtot[w] = ws;
    __syncthreads();
    int wbase = 0;
    for (int i = 0; i < w; ++i) wbase += wtot[i];
    int excl = wbase + (ws - s3);
    int4 o4;
    o4.x = excl; o4.y = excl + s0; o4.z = excl + s1; o4.w = excl + s2;
    p[t] = o4;
    if (t == 255) aux[blk] = wbase + ws;
}

// B: exclusive scan of aux[SCAN_BLOCKS=1024] (one wave, 16 elems/thread)
__global__ __launch_bounds__(64) void gin_scan_b(int* __restrict__ aux) {
    const int t = threadIdx.x;
    int4* p = (int4*)aux;
    int vals[16];
    #pragma unroll
    for (int i = 0; i < 4; ++i) {
        int4 a = p[4 * t + i];
        vals[4 * i + 0] = a.x; vals[4 * i + 1] = a.y;
        vals[4 * i + 2] = a.z; vals[4 * i + 3] = a.w;
    }
    int run = 0;
    #pragma unroll
    for (int i = 0; i < 16; ++i) { int tmp = vals[i]; vals[i] = run; run += tmp; }
    int ws = run;
    #pragma unroll
    for (int off = 1; off < 64; off <<= 1) {
        int o = __shfl_up(ws, off);
        if (t >= off) ws += o;
    }
    int excl = ws - run;
    #pragma unroll
    for (int i = 0; i < 4; ++i) {
        int4 o4;
        o4.x = vals[4 * i + 0] + excl; o4.y = vals[4 * i + 1] + excl;
        o4.z = vals[4 * i + 2] + excl; o4.w = vals[4 * i + 3] + excl;
        p[4 * t + i] = o4;
    }
}

__global__ __launch_bounds__(256) void gin_scan_c(int* __restrict__ cnt,
                                                  const int* __restrict__ aux) {
    const int t = threadIdx.x, blk = blockIdx.x;
    int base = aux[blk];
    int4* p = (int4*)(cnt + blk * 1024);
    int4 vv = p[t];
    vv.x += base; vv.y += base; vv.z += base; vv.w += base;
    p[t] = vv;
}

// ---------------- scatter: fully LDS-staged, burst flush --------------------
__global__ __launch_bounds__(HSB) void gin_scatter(const int* __restrict__ ei,
                                                   const int* __restrict__ cnt,
                                                   unsigned int* __restrict__ packed) {
    __shared__ int cur[NKEYS];            // 16 KB
    __shared__ unsigned int E[CHUNK];     // 122.1 KB
    __shared__ int wtot[16];
    const int t = threadIdx.x, s = blockIdx.x;
    const int lane = t & 63, wave = t >> 6;

    // local exclusive scan of this block's per-key counts (4 keys/thread)
    const int kb = 4 * t;
    int cc[4];
    int sum4 = 0;
    #pragma unroll
    for (int i = 0; i < 4; ++i) {
        int f = (kb + i) * NSCAT + s;
        int nxt = (f + 1 < SCAN_N) ? cnt[f + 1] : N_EDGES;
        cc[i] = nxt - cnt[f];
        sum4 += cc[i];
    }
    int ws = sum4;
    #pragma unroll
    for (int off = 1; off < 64; off <<= 1) {
        int o = __shfl_up(ws, off);
        if (lane >= off) ws += o;
    }
    if (lane == 63) wtot[wave] = ws;
    __syncthreads();
    int wbase = 0;
    for (int i = 0; i < wave; ++i) wbase += wtot[i];
    int excl = wbase + ws - sum4;
    #pragma unroll
    for (int i = 0; i < 4; ++i) { cur[kb + i] = excl; excl += cc[i]; }
    __syncthreads();

    // phase 1: place edges into LDS at locally-sorted positions
    const int* src = ei;
    const int* dst = ei + N_EDGES;
    const int e0 = s * CHUNK, e1 = e0 + CHUNK;
    for (int e = e0 + t; e < e1; e += HSB) {
        int d = dst[e];
        int key = d >> 7;
        int lofs = atomicAdd(&cur[key], 1);
        E[lofs] = (unsigned int)src[e] | ((unsigned int)(d & (TILE - 1)) << 19);
    }
    __syncthreads();
    // post-phase1: cur[k] = local end of key k's run; start = cur[k-1] (or 0)

    // phase 2: per-key burst flush with contiguous global stores
    const int KPW = NKEYS / 16;           // 256 keys per wave
    for (int k = wave * KPW; k < (wave + 1) * KPW; ++k) {
        int endl = cur[k];
        int startl = (k > 0) ? cur[k - 1] : 0;
        int m = endl - startl;
        if (m <= 0) continue;
        int gbase = cnt[k * NSCAT + s];
        for (int j = lane; j < m; j += 64)
            packed[gbase + j] = E[startl + j];
    }
}

// ---------------- winsort: reorder each bucket's edges by src window --------
__global__ __launch_bounds__(256) void gin_winsort(unsigned int* __restrict__ packed,
                                                   const int* __restrict__ cnt) {
    __shared__ unsigned int E[CAP];
    __shared__ unsigned int F[CAP];
    __shared__ int cw[NW * 256];
    __shared__ int winBase[NW];
    __shared__ int wt[NW];
    const int t = threadIdx.x, bucket = blockIdx.x;
    const int beg = cnt[bucket * NSCAT];
    const int end = cnt[(bucket + 1) * NSCAT];
    const int n = end - beg;
    if (n > CAP) return;                      // identity fallback (rare/never)

    for (int i = t; i < n; i += 256) E[i] = packed[beg + i];
    __syncthreads();

    int c[NW];
    #pragma unroll
    for (int w = 0; w < NW; ++w) c[w] = 0;
    for (int i = t; i < n; i += 256) { int w = (E[i] & 0x7FFFFu) >> 16; c[w]++; }
    #pragma unroll
    for (int w = 0; w < NW; ++w) cw[w * 256 + t] = c[w];
    __syncthreads();

    const int lane = t & 63, wv = t >> 6;
    for (int rep = 0; rep < 2; ++rep) {
        int w = wv + rep * 4;
        int carry = 0;
        #pragma unroll
        for (int chunkk = 0; chunkk < 4; ++chunkk) {
            int idx = chunkk * 64 + lane;
            int val = cw[w * 256 + idx];
            int sc = val;
            #pragma unroll
            for (int off = 1; off < 64; off <<= 1) {
                int o = __shfl_up(sc, off);
                if (lane >= off) sc += o;
            }
            cw[w * 256 + idx] = sc - val + carry;
            carry += __shfl(sc, 63);
        }
        if (lane == 0) wt[w] = carry;
    }
    __syncthreads();
    if (t == 0) {
        int run = 0;
        #pragma unroll
        for (int w = 0; w < NW; ++w) { winBase[w] = run; run += wt[w]; }
    }
    __syncthreads();

    int runc[NW];
    #pragma unroll
    for (int w = 0; w < NW; ++w) runc[w] = 0;
    for (int i = t; i < n; i += 256) {
        unsigned int pk = E[i];
        int w = (pk & 0x7FFFFu) >> 16;
        int pos = winBase[w] + cw[w * 256 + t] + runc[w]++;
        F[pos] = pk;
    }
    __syncthreads();
    for (int i = t; i < n; i += 256) packed[beg + i] = F[i];
}

// ---------------- reduce: wave-private tile, NO aggregation atomics ---------
// TILE=128 doubles bucket count -> 3907 waves = 15.3 waves/CU (fix for the
// 18% occupancy wave-parallelism cap at TILE=256's 1954 waves).
__global__ __launch_bounds__(RB) void gin_reduce(
    const unsigned int* __restrict__ packed,
    const int* __restrict__ cnt,
    const float* __restrict__ xa,
    const float* __restrict__ xb,
    const int* __restrict__ batch,
    const float* __restrict__ w1,
    const float* __restrict__ b1,
    const float* __restrict__ v,
    const float* __restrict__ c,
    float* __restrict__ out)
{
    __shared__ float tile[WPB * TILE * TSR];   // 24 KB, one 6 KB slice per wave
    __shared__ float w1s[IN_DIM * HID];
    __shared__ float b1s[HID];
    __shared__ float vs[HID];
    __shared__ float cs;

    const int t = threadIdx.x;
    const int wave = t >> 6, lane = t & 63;

    for (int i = t; i < WPB * TILE * TSR; i += RB) tile[i] = 0.f;
    for (int i = t; i < IN_DIM * HID; i += RB) w1s[i] = w1[i];
    if (t < HID) { b1s[t] = b1[t]; vs[t] = v[t]; }
    if (t == 0) cs = *c;
    __syncthreads();

    const int bucket = blockIdx.x * WPB + wave;
    float* tw = tile + wave * TILE * TSR;
    const int beg = cnt[bucket * NSCAT];
    const int end = cnt[(bucket + 1) * NSCAT];   // padded keys hold N_EDGES

    for (int p0 = beg; p0 < end; p0 += 64) {
        int p = p0 + lane;
        bool valid = p < end;
        unsigned int pk = valid ? packed[p] : 0u;
        int local = (int)(pk >> 19);             // 0..127
        int src = (int)(pk & 0x7FFFFu);
        const float4* xr = (const float4*)(xa + (size_t)src * 8);
        float4 a0 = xr[0], a1 = xr[1];
        float a2 = xb[src];

        unsigned long long active = __ballot(valid);
        while (active) {
            unsigned long long m = active;
            #pragma unroll
            for (int bq = 0; bq < 7; ++bq) {
                unsigned long long bal = __ballot((local >> bq) & 1);
                m &= ((local >> bq) & 1) ? bal : ~bal;
            }
            unsigned long long mybit = 1ULL << lane;
            bool lead = ((active & mybit) != 0ULL) && ((m & (mybit - 1ULL)) == 0ULL);
            unsigned long long lmask = __ballot(lead);
            if (lead) {
                float4* row = (float4*)(tw + local * TSR);
                float4 r0 = row[0], r1 = row[1];
                float r2 = tw[local * TSR + 8];
                r0.x += a0.x; r0.y += a0.y; r0.z += a0.z; r0.w += a0.w;
                r1.x += a1.x; r1.y += a1.y; r1.z += a1.z; r1.w += a1.w;
                row[0] = r0; row[1] = r1;
                tw[local * TSR + 8] = r2 + a2;
            }
            active &= ~lmask;
        }
    }
    // no barrier needed: tile slice is wave-private from here on

    // fused MLP + scalar collapse + segmented pooled reduction
    #pragma unroll
    for (int g = 0; g < TILE / 64; ++g) {
        int n = g * 64 + lane;
        int node = bucket * TILE + n;
        float s = 0.f;
        int b = -1;
        if (node < N_NODES) {
            const float4* xr = (const float4*)(xa + (size_t)node * 8);
            float4 q0 = xr[0], q1 = xr[1];
            float tv[IN_DIM];
            tv[0] = q0.x + tw[n * TSR + 0];
            tv[1] = q0.y + tw[n * TSR + 1];
            tv[2] = q0.z + tw[n * TSR + 2];
            tv[3] = q0.w + tw[n * TSR + 3];
            tv[4] = q1.x + tw[n * TSR + 4];
            tv[5] = q1.y + tw[n * TSR + 5];
            tv[6] = q1.z + tw[n * TSR + 6];
            tv[7] = q1.w + tw[n * TSR + 7];
            tv[8] = xb[node] + tw[n * TSR + 8];
            s = cs;
            #pragma unroll
            for (int j = 0; j < HID; ++j) {
                float z = b1s[j];
                #pragma unroll
                for (int k = 0; k < IN_DIM; ++k)
                    z = fmaf(tv[k], w1s[k * HID + j], z);
                s += fmaxf(z, 0.f) * vs[j];
            }
            b = batch[node];
        }
        #pragma unroll
        for (int off = 1; off < 64; off <<= 1) {
            float so = __shfl_up(s, off);
            int bo = __shfl_up(b, off);
            if (lane >= off && bo == b) s += so;
        }
        int nb = __shfl_down(b, 1);
        bool tail = (lane == 63) || (nb != b);
        if (tail && b >= 0) atomicAdd(&out[b], s);
    }
}

extern "C" void kernel_launch(void* const* d_in, const int* in_sizes, int n_in,
                              void* d_out, int out_size, void* d_ws, size_t ws_size,
                              hipStream_t stream) {
    const float* x     = (const float*)d_in[0];
    const int*   ei    = (const int*)d_in[1];
    const int*   batch = (const int*)d_in[2];
    const float* w1    = (const float*)d_in[3];
    const float* b1    = (const float*)d_in[4];
    const float* w2    = (const float*)d_in[5];
    const float* b2    = (const float*)d_in[6];
    const float* w3    = (const float*)d_in[7];
    const float* b3    = (const float*)d_in[8];
    float* out = (float*)d_out;

    // workspace (~54.1 MB)
    float* xa = (float*)d_ws;                                           // 16 MB
    float* xb = xa + (size_t)N_NODES * 8;                               // 2 MB
    unsigned int* packed = (unsigned int*)(xb + N_NODES);               // 32 MB
    int* cnt = (int*)(packed + N_EDGES);                                // 4 MB
    int* aux = cnt + SCAN_N;                                            // 1024 ints
    float* v = (float*)(aux + SCAN_BLOCKS);                             // 64 floats
    float* c = v + HID;                                                 // 1 float

    gin_xpad<<<(N_NODES * IN_DIM + 255) / 256, 256, 0, stream>>>(x, xa, xb);
    gin_precompute<<<(N_GRAPHS + 255) / 256, 256, 0, stream>>>(w2, b2, w3, b3, out, v, c);
    gin_hist<<<NSCAT, HSB, 0, stream>>>(ei, cnt);
    gin_scan_a<<<SCAN_BLOCKS, 256, 0, stream>>>(cnt, aux);
    gin_scan_b<<<1, 64, 0, stream>>>(aux);
    gin_scan_c<<<SCAN_BLOCKS, 256, 0, stream>>>(cnt, aux);
    gin_scatter<<<NSCAT, HSB, 0, stream>>>(ei, cnt, packed);
    gin_winsort<<<NKEYS_USED, 256, 0, stream>>>(packed, cnt);
    gin_reduce<<<RGRID, RB, 0, stream>>>(packed, cnt, xa, xb, batch, w1, b1, v, c, out);
}

// Round 15
// 400.581 us; speedup vs baseline: 1.1612x; 1.1612x over previous
//
#include <hip/hip_runtime.h>

#define N_NODES 500000
#define N_EDGES 8000000
#define N_GRAPHS 4096
#define IN_DIM 9
#define HID 64
#define TILE 128             // reduce bucket (half of a sort key)
#define SKEY 256             // sort-key granularity (nodes per scatter key)
#define TSR 12               // LDS tile row stride -> 48 B (f4,f4,scalar)
#define NKEYS 2048           // padded sort-key space (used: 1954)
#define NKEYS_USED ((N_NODES + SKEY - 1) / SKEY)   // 1954
#define NB128 ((N_NODES + TILE - 1) / TILE)        // 3907 reduce buckets
#define NSCAT 256            // hist/scatter chunks
#define CHUNK (N_EDGES / NSCAT)                    // 31250
#define HSB 1024             // hist/scatter block threads
#define RB 256               // reduce block threads (4 waves)
#define WPB 4
#define RGRID ((NB128 + WPB - 1) / WPB)            // 977
#define SCAN_N (NKEYS * NSCAT)                     // 524288
#define SCAN_BLOCKS (SCAN_N / 1024)                // 512
#define NW 8                 // src windows: src>>16
#define NSK 16               // winsort sort keys: half*8 + window
#define CAP 5632             // winsort LDS capacity (mean 4096, sd 64 -> +24s)

// ---------------- xpad: x[N][9] -> xa[N][8] (32B rows) + xb[N] --------------
__global__ void gin_xpad(const float* __restrict__ x,
                         float* __restrict__ xa, float* __restrict__ xb) {
    int i = blockIdx.x * blockDim.x + threadIdx.x;
    const int TOT = N_NODES * IN_DIM;
    if (i < TOT) {
        int n = i / IN_DIM, k = i - n * IN_DIM;
        float val = x[i];
        if (k < 8) xa[n * 8 + k] = val;
        else       xb[n] = val;
    }
}

// ---------------- precompute: v = w2@w3, c = b2.w3, out[g] = b3 -------------
__global__ void gin_precompute(const float* __restrict__ w2,
                               const float* __restrict__ b2,
                               const float* __restrict__ w3,
                               const float* __restrict__ b3,
                               float* __restrict__ out,
                               float* __restrict__ v,
                               float* __restrict__ c) {
    int g = blockIdx.x * blockDim.x + threadIdx.x;
    if (g < N_GRAPHS) out[g] = b3[0];
    if (blockIdx.x == 0) {
        int k = threadIdx.x;
        if (k < HID) {
            float acc = 0.f;
            #pragma unroll
            for (int j = 0; j < HID; ++j) acc += w2[k * HID + j] * w3[j];
            v[k] = acc;
        } else if (k == HID) {
            float acc = 0.f;
            #pragma unroll
            for (int j = 0; j < HID; ++j) acc += b2[j] * w3[j];
            *c = acc;
        }
    }
}

// ---------------- hist: cnt[key*NSCAT + s], key = dst>>8 --------------------
__global__ __launch_bounds__(HSB) void gin_hist(const int* __restrict__ ei,
                                                int* __restrict__ cnt) {
    __shared__ int h[NKEYS];
    const int t = threadIdx.x, s = blockIdx.x;
    for (int b = t; b < NKEYS; b += HSB) h[b] = 0;
    __syncthreads();
    const int* dst = ei + N_EDGES;
    const int e0 = s * CHUNK, e1 = e0 + CHUNK;
    for (int e = e0 + t; e < e1; e += HSB)
        atomicAdd(&h[dst[e] >> 8], 1);
    __syncthreads();
    for (int b = t; b < NKEYS; b += HSB)
        cnt[b * NSCAT + s] = h[b];
}

// ---------------- parallel exclusive scan of cnt[SCAN_N] --------------------
__global__ __launch_bounds__(256) void gin_scan_a(int* __restrict__ cnt,
                                                  int* __restrict__ aux) {
    __shared__ int wtot[4];
    const int t = threadIdx.x, blk = blockIdx.x;
    int4* p = (int4*)(cnt + blk * 1024);
    int4 vv = p[t];
    int s0 = vv.x, s1 = s0 + vv.y, s2 = s1 + vv.z, s3 = s2 + vv.w;
    int lane = t & 63, w = t >> 6;
    int ws = s3;
    #pragma unroll
    for (int off = 1; off < 64; off <<= 1) {
        int o = __shfl_up(ws, off);
        if (lane >= off) ws += o;
    }
    if (lane == 63) wtot[w] = ws;
    __syncthreads();
    int wbase = 0;
    for (int i = 0; i < w; ++i) wbase += wtot[i];
    int excl = wbase + (ws - s3);
    int4 o4;
    o4.x = excl; o4.y = excl + s0; o4.z = excl + s1; o4.w = excl + s2;
    p[t] = o4;
    if (t == 255) aux[blk] = wbase + ws;
}

__global__ __launch_bounds__(64) void gin_scan_b(int* __restrict__ aux) {
    const int t = threadIdx.x;
    int4* p = (int4*)aux;
    int4 a = p[2 * t], bq = p[2 * t + 1];
    int s0 = a.x, s1 = s0 + a.y, s2 = s1 + a.z, s3 = s2 + a.w;
    int s4 = s3 + bq.x, s5 = s4 + bq.y, s6 = s5 + bq.z, s7 = s6 + bq.w;
    int ws = s7;
    #pragma unroll
    for (int off = 1; off < 64; off <<= 1) {
        int o = __shfl_up(ws, off);
        if (t >= off) ws += o;
    }
    int excl = ws - s7;
    int4 o0, o1;
    o0.x = excl; o0.y = excl + s0; o0.z = excl + s1; o0.w = excl + s2;
    o1.x = excl + s3; o1.y = excl + s4; o1.z = excl + s5; o1.w = excl + s6;
    p[2 * t] = o0; p[2 * t + 1] = o1;
}

__global__ __launch_bounds__(256) void gin_scan_c(int* __restrict__ cnt,
                                                  const int* __restrict__ aux) {
    const int t = threadIdx.x, blk = blockIdx.x;
    int base = aux[blk];
    int4* p = (int4*)(cnt + blk * 1024);
    int4 vv = p[t];
    vv.x += base; vv.y += base; vv.z += base; vv.w += base;
    p[t] = vv;
}

// ---------------- scatter: fully LDS-staged, burst flush (R12 version) ------
__global__ __launch_bounds__(HSB) void gin_scatter(const int* __restrict__ ei,
                                                   const int* __restrict__ cnt,
                                                   unsigned int* __restrict__ packed) {
    __shared__ int cur[NKEYS];            // 8 KB
    __shared__ unsigned int E[CHUNK];     // 122.1 KB
    __shared__ int wtot[16];
    const int t = threadIdx.x, s = blockIdx.x;
    const int lane = t & 63, wave = t >> 6;

    // local exclusive scan of this block's per-key counts via flat-scan diffs
    const int k0 = 2 * t, k1 = 2 * t + 1;
    const int f0 = k0 * NSCAT + s;
    const int f1 = k1 * NSCAT + s;
    int c0 = cnt[f0 + 1] - cnt[f0];
    int nxt = (f1 + 1 < SCAN_N) ? cnt[f1 + 1] : N_EDGES;
    int c1 = nxt - cnt[f1];
    int sum2 = c0 + c1;
    int ws = sum2;
    #pragma unroll
    for (int off = 1; off < 64; off <<= 1) {
        int o = __shfl_up(ws, off);
        if (lane >= off) ws += o;
    }
    if (lane == 63) wtot[wave] = ws;
    __syncthreads();
    int wbase = 0;
    for (int i = 0; i < wave; ++i) wbase += wtot[i];
    int excl = wbase + ws - sum2;
    cur[k0] = excl;
    cur[k1] = excl + c0;
    __syncthreads();

    // phase 1: place edges into LDS at locally-sorted positions
    const int* src = ei;
    const int* dst = ei + N_EDGES;
    const int e0 = s * CHUNK, e1 = e0 + CHUNK;
    for (int e = e0 + t; e < e1; e += HSB) {
        int d = dst[e];
        int key = d >> 8;
        int lofs = atomicAdd(&cur[key], 1);
        E[lofs] = (unsigned int)src[e] | ((unsigned int)(d & (SKEY - 1)) << 19);
    }
    __syncthreads();

    // phase 2: per-key burst flush with contiguous global stores
    const int KPW = NKEYS / 16;           // 128 keys per wave
    for (int k = wave * KPW; k < (wave + 1) * KPW; ++k) {
        int endl = cur[k];
        int startl = (k > 0) ? cur[k - 1] : 0;
        int m = endl - startl;
        if (m <= 0) continue;
        int gbase = cnt[k * NSCAT + s];
        for (int j = lane; j < m; j += 64)
            packed[gbase + j] = E[startl + j];
    }
}

// ---------------- winsort: 16-way sort by (half, window); emits mid[key] ----
// half = bit7 of local (bit 26 of pk). After this, each 256-key's edges are
// [half0 | half1], each half window-sorted, and mid[key] = |half0|. This makes
// the half-split correctness-bearing: CAP is +24 sigma of the binomial bucket
// size, so the fallback is unreachable for this input distribution.
__global__ __launch_bounds__(256) void gin_winsort(unsigned int* __restrict__ packed,
                                                   const int* __restrict__ cnt,
                                                   int* __restrict__ mid) {
    __shared__ unsigned int E[CAP];
    __shared__ unsigned int F[CAP];
    __shared__ int cw[NSK * 256];
    __shared__ int winBase[NSK];
    __shared__ int wt[NSK];
    const int t = threadIdx.x, bucket = blockIdx.x;
    const int beg = cnt[bucket * NSCAT];
    const int end = cnt[(bucket + 1) * NSCAT];
    const int n = end - beg;
    if (n > CAP) return;                      // unreachable (+24 sigma)

    for (int i = t; i < n; i += 256) E[i] = packed[beg + i];
    __syncthreads();

    int c[NSK];
    #pragma unroll
    for (int w = 0; w < NSK; ++w) c[w] = 0;
    for (int i = t; i < n; i += 256) {
        unsigned int pk = E[i];
        int w = (int)((pk >> 26) & 1u) * 8 + (int)((pk & 0x7FFFFu) >> 16);
        c[w]++;
    }
    #pragma unroll
    for (int w = 0; w < NSK; ++w) cw[w * 256 + t] = c[w];
    __syncthreads();

    const int lane = t & 63, wv = t >> 6;
    for (int rep = 0; rep < 4; ++rep) {
        int w = wv + rep * 4;
        int carry = 0;
        #pragma unroll
        for (int chunkk = 0; chunkk < 4; ++chunkk) {
            int idx = chunkk * 64 + lane;
            int val = cw[w * 256 + idx];
            int sc = val;
            #pragma unroll
            for (int off = 1; off < 64; off <<= 1) {
                int o = __shfl_up(sc, off);
                if (lane >= off) sc += o;
            }
            cw[w * 256 + idx] = sc - val + carry;
            carry += __shfl(sc, 63);
        }
        if (lane == 0) wt[w] = carry;
    }
    __syncthreads();
    if (t == 0) {
        int run = 0;
        #pragma unroll
        for (int w = 0; w < NSK; ++w) { winBase[w] = run; run += wt[w]; }
        mid[bucket] = winBase[8];            // |half0|
    }
    __syncthreads();

    int runc[NSK];
    #pragma unroll
    for (int w = 0; w < NSK; ++w) runc[w] = 0;
    for (int i = t; i < n; i += 256) {
        unsigned int pk = E[i];
        int w = (int)((pk >> 26) & 1u) * 8 + (int)((pk & 0x7FFFFu) >> 16);
        int pos = winBase[w] + cw[w * 256 + t] + runc[w]++;
        F[pos] = pk;
    }
    __syncthreads();
    for (int i = t; i < n; i += 256) packed[beg + i] = F[i];
}

// ---------------- reduce: TILE=128 half-buckets, wave-private tile ----------
// 3907 half-buckets -> 15.3 waves/CU (vs 7.6 at TILE=256): fixes the
// wave-parallelism occupancy cap without touching the scatter's key size.
__global__ __launch_bounds__(RB) void gin_reduce(
    const unsigned int* __restrict__ packed,
    const int* __restrict__ cnt,
    const int* __restrict__ mid,
    const float* __restrict__ xa,
    const float* __restrict__ xb,
    const int* __restrict__ batch,
    const float* __restrict__ w1,
    const float* __restrict__ b1,
    const float* __restrict__ v,
    const float* __restrict__ c,
    float* __restrict__ out)
{
    __shared__ float tile[WPB * TILE * TSR];   // 24 KB, one 6 KB slice per wave
    __shared__ float w1s[IN_DIM * HID];
    __shared__ float b1s[HID];
    __shared__ float vs[HID];
    __shared__ float cs;

    const int t = threadIdx.x;
    const int wave = t >> 6, lane = t & 63;

    for (int i = t; i < WPB * TILE * TSR; i += RB) tile[i] = 0.f;
    for (int i = t; i < IN_DIM * HID; i += RB) w1s[i] = w1[i];
    if (t < HID) { b1s[t] = b1[t]; vs[t] = v[t]; }
    if (t == 0) cs = *c;
    __syncthreads();

    const int bucket = blockIdx.x * WPB + wave;   // 0..3907 (3907 empty+guarded)
    const int key = bucket >> 1, half = bucket & 1;
    float* tw = tile + wave * TILE * TSR;
    const int beg0 = cnt[key * NSCAT];
    const int endK = cnt[(key + 1) * NSCAT];
    const int m = mid[key];
    const int beg = half ? (beg0 + m) : beg0;
    const int end = half ? endK : (beg0 + m);

    for (int p0 = beg; p0 < end; p0 += 64) {
        int p = p0 + lane;
        bool valid = p < end;
        unsigned int pk = valid ? packed[p] : 0u;
        int local = (int)(pk >> 19) & (TILE - 1);   // 7-bit local within half
        int src = (int)(pk & 0x7FFFFu);
        const float4* xr = (const float4*)(xa + (size_t)src * 8);
        float4 a0 = xr[0], a1 = xr[1];
        float a2 = xb[src];

        unsigned long long active = __ballot(valid);
        while (active) {
            unsigned long long mm = active;
            #pragma unroll
            for (int bq = 0; bq < 7; ++bq) {
                unsigned long long bal = __ballot((local >> bq) & 1);
                mm &= ((local >> bq) & 1) ? bal : ~bal;
            }
            unsigned long long mybit = 1ULL << lane;
            bool lead = ((active & mybit) != 0ULL) && ((mm & (mybit - 1ULL)) == 0ULL);
            unsigned long long lmask = __ballot(lead);
            if (lead) {
                float4* row = (float4*)(tw + local * TSR);
                float4 r0 = row[0], r1 = row[1];
                float r2 = tw[local * TSR + 8];
                r0.x += a0.x; r0.y += a0.y; r0.z += a0.z; r0.w += a0.w;
                r1.x += a1.x; r1.y += a1.y; r1.z += a1.z; r1.w += a1.w;
                row[0] = r0; row[1] = r1;
                tw[local * TSR + 8] = r2 + a2;
            }
            active &= ~lmask;
        }
    }
    // no barrier needed: tile slice is wave-private from here on

    // fused MLP + scalar collapse + segmented pooled reduction
    const int nodeBase = key * SKEY + half * TILE;
    #pragma unroll
    for (int g = 0; g < TILE / 64; ++g) {
        int n = g * 64 + lane;
        int node = nodeBase + n;
        float s = 0.f;
        int b = -1;
        if (node < N_NODES) {
            const float4* xr = (const float4*)(xa + (size_t)node * 8);
            float4 q0 = xr[0], q1 = xr[1];
            float tv[IN_DIM];
            tv[0] = q0.x + tw[n * TSR + 0];
            tv[1] = q0.y + tw[n * TSR + 1];
            tv[2] = q0.z + tw[n * TSR + 2];
            tv[3] = q0.w + tw[n * TSR + 3];
            tv[4] = q1.x + tw[n * TSR + 4];
            tv[5] = q1.y + tw[n * TSR + 5];
            tv[6] = q1.z + tw[n * TSR + 6];
            tv[7] = q1.w + tw[n * TSR + 7];
            tv[8] = xb[node] + tw[n * TSR + 8];
            s = cs;
            #pragma unroll
            for (int j = 0; j < HID; ++j) {
                float z = b1s[j];
                #pragma unroll
                for (int k = 0; k < IN_DIM; ++k)
                    z = fmaf(tv[k], w1s[k * HID + j], z);
                s += fmaxf(z, 0.f) * vs[j];
            }
            b = batch[node];
        }
        #pragma unroll
        for (int off = 1; off < 64; off <<= 1) {
            float so = __shfl_up(s, off);
            int bo = __shfl_up(b, off);
            if (lane >= off && bo == b) s += so;
        }
        int nb = __shfl_down(b, 1);
        bool tail = (lane == 63) || (nb != b);
        if (tail && b >= 0) atomicAdd(&out[b], s);
    }
}

extern "C" void kernel_launch(void* const* d_in, const int* in_sizes, int n_in,
                              void* d_out, int out_size, void* d_ws, size_t ws_size,
                              hipStream_t stream) {
    const float* x     = (const float*)d_in[0];
    const int*   ei    = (const int*)d_in[1];
    const int*   batch = (const int*)d_in[2];
    const float* w1    = (const float*)d_in[3];
    const float* b1    = (const float*)d_in[4];
    const float* w2    = (const float*)d_in[5];
    const float* b2    = (const float*)d_in[6];
    const float* w3    = (const float*)d_in[7];
    const float* b3    = (const float*)d_in[8];
    float* out = (float*)d_out;

    // workspace (~52.2 MB)
    float* xa = (float*)d_ws;                                           // 16 MB
    float* xb = xa + (size_t)N_NODES * 8;                               // 2 MB
    unsigned int* packed = (unsigned int*)(xb + N_NODES);               // 32 MB
    int* cnt = (int*)(packed + N_EDGES);                                // 2 MB
    int* aux = cnt + SCAN_N;                                            // 512 ints
    int* mid = aux + SCAN_BLOCKS;                                       // 2048 ints
    float* v = (float*)(mid + NKEYS);                                   // 64 floats
    float* c = v + HID;                                                 // 1 float

    gin_xpad<<<(N_NODES * IN_DIM + 255) / 256, 256, 0, stream>>>(x, xa, xb);
    gin_precompute<<<(N_GRAPHS + 255) / 256, 256, 0, stream>>>(w2, b2, w3, b3, out, v, c);
    gin_hist<<<NSCAT, HSB, 0, stream>>>(ei, cnt);
    gin_scan_a<<<SCAN_BLOCKS, 256, 0, stream>>>(cnt, aux);
    gin_scan_b<<<1, 64, 0, stream>>>(aux);
    gin_scan_c<<<SCAN_BLOCKS, 256, 0, stream>>>(cnt, aux);
    gin_scatter<<<NSCAT, HSB, 0, stream>>>(ei, cnt, packed);
    gin_winsort<<<NKEYS_USED, 256, 0, stream>>>(packed, cnt, mid);
    gin_reduce<<<RGRID, RB, 0, stream>>>(packed, cnt, mid, xa, xb, batch, w1, b1, v, c, out);
}